// Round 4
// baseline (191.429 us; speedup 1.0000x reference)
//
#include <hip/hip_runtime.h>
#include <hip/hip_bf16.h>

// Problem constants (fixed by reference)
#define BB 32
#define DD 64
#define HWHW 4096
#define NPOS 131072
#define NELEM (NPOS * DD)          // 8388608
#define KK 512
#define LOSS_SCALE (1.2f / 8388608.f)
#define DELTA 2.0f                  // >= 2*eps(bf16 dot) incl. 5-sigma margin
#define QCAP 2048
#define PT 2                        // position-tiles per wave
#define POSB 128                    // positions per block (4 waves * PT * 16)
#define NBLK (NPOS / POSB)          // 1024 blocks = 4 blocks/CU -> 4 waves/SIMD

typedef __attribute__((ext_vector_type(8))) short short8v;   // 8 bf16
typedef __attribute__((ext_vector_type(4))) float float4v;   // MFMA acc

__device__ inline unsigned short f2bf(float f) {             // fp32->bf16 RNE
    unsigned u = __float_as_uint(f);
    unsigned r = u + 0x7FFFu + ((u >> 16) & 1u);
    return (unsigned short)(r >> 16);
}
__device__ inline float bf2f(unsigned short s) {
    return __uint_as_float(((unsigned)s) << 16);
}
__device__ inline unsigned f2o(float f) {                    // order-preserving f32->u32
    unsigned u = __float_as_uint(f);
    return ((int)u < 0) ? ~u : (u | 0x80000000u);
}

// ---------------------------------------------------------------------------
// Prep: E fp32 -> bf16 (RNE) into ws; ne2h[k] = -0.5*|e_k|^2 fp32 (negated so
// it drops straight into the MFMA C-operand).
// ---------------------------------------------------------------------------
__global__ __launch_bounds__(256) void vq_prep(const float* __restrict__ emb,
                                               unsigned short* __restrict__ ebf,
                                               float* __restrict__ ne2h) {
    const int t = blockIdx.x * 256 + threadIdx.x;   // 0..8191
    const int row = t >> 4, c = t & 15;
    const float4 v = *(const float4*)(emb + row * DD + c * 4);
    unsigned u0 = (unsigned)f2bf(v.x) | ((unsigned)f2bf(v.y) << 16);
    unsigned u1 = (unsigned)f2bf(v.z) | ((unsigned)f2bf(v.w) << 16);
    *(uint2*)(ebf + row * DD + c * 4) = make_uint2(u0, u1);
    float p = v.x * v.x + v.y * v.y + v.z * v.z + v.w * v.w;
    p += __shfl_xor(p, 1, 64); p += __shfl_xor(p, 2, 64);
    p += __shfl_xor(p, 4, 64); p += __shfl_xor(p, 8, 64);
    if (c == 0) ne2h[row] = -0.5f * p;
}

// ---------------------------------------------------------------------------
// Main: block = 128 positions, 4 waves x 2 pos-tiles; grid 1024 (4 blocks/CU
// -> 4 waves/SIMD for latency hiding; R3 ran 1 wave/SIMD and stalled 90%).
// Scores S^T = E_bf16 * X_bf16^T via mfma_f32_16x16x32_bf16 with C = -e2/2.
//   A-frag (E): lane reads 16B at ebf[row=ct*16+(l&15)][(l>>4)*8 + h*32],
//   B-frag (X): elem j <-> d = h*32+(l>>4)*8+j (same k-mapping -> permutation
//   cancels). C/D: col=l&15=position, row=(l>>4)*4+r=code (m89).
// Pass1: per-position max score. Pass2: bitwise-identical recompute, enqueue
// codes within DELTA. Drain: fp32 rescore, packed-key LDS atomicMax
// (monotone float | (511-k) => first-min-index tie rule).
// ---------------------------------------------------------------------------
__global__ __launch_bounds__(256, 4) void vq_main(
        const float* __restrict__ feat,
        const float* __restrict__ emb,
        const unsigned short* __restrict__ ebf,
        const float* __restrict__ ne2h,
        float* __restrict__ out,
        float* __restrict__ loss) {

    __shared__ unsigned long long sbest[POSB];
    __shared__ unsigned qbuf[QCAP];
    __shared__ unsigned qcnt;
    __shared__ float wsum[4];

    const int tid = threadIdx.x;
    const int wid = tid >> 6, lane = tid & 63;
    const int l15 = lane & 15, lg = lane >> 4;

    if (tid < POSB) sbest[tid] = 0ull;
    if (tid == 0) qcnt = 0u;

    const int pbase = blockIdx.x * POSB;
    const int b     = pbase >> 12;
    const int hwb   = pbase & 4095;
    const float* featB = feat + (size_t)b * DD * HWHW;
    float*       outB  = out  + (size_t)b * DD * HWHW;
    const int wbase = wid * (PT * 16);   // 32 positions per wave

    // ---- build B-frags: x bf16 (RNE), PT pos-tiles x 2 k-halves ----
    short8v bx[PT][2];
#pragma unroll
    for (int pt = 0; pt < PT; ++pt) {
        const int hw = hwb + wbase + pt * 16 + l15;
#pragma unroll
        for (int h = 0; h < 2; ++h) {
            float xv[8];
#pragma unroll
            for (int j = 0; j < 8; ++j) {
                const int d = h * 32 + lg * 8 + j;
                xv[j] = featB[(size_t)d * HWHW + hw];
            }
            short8v s;
#pragma unroll
            for (int j = 0; j < 8; ++j) s[j] = (short)f2bf(xv[j]);
            bx[pt][h] = s;
        }
    }

    __syncthreads();   // LDS init visible

    const char* ebfB = (const char*)ebf;

    // ---- pass 1: per-position max score ----
    float M[PT];
#pragma unroll
    for (int pt = 0; pt < PT; ++pt) M[pt] = -3.0e38f;

    short8v a0n = *(const short8v*)(ebfB + l15 * 128 + lg * 16);
    short8v a1n = *(const short8v*)(ebfB + l15 * 128 + 64 + lg * 16);
    float4v ne2n = *(const float4v*)(ne2h + lg * 4);

    for (int ct = 0; ct < 32; ++ct) {
        const short8v a0c = a0n, a1c = a1n;
        const float4v ne2c = ne2n;
        if (ct < 31) {
            const char* p = ebfB + ((ct + 1) * 16 + l15) * 128 + lg * 16;
            a0n = *(const short8v*)p;
            a1n = *(const short8v*)(p + 64);
            ne2n = *(const float4v*)(ne2h + (ct + 1) * 16 + lg * 4);
        }
        float4v acc[PT];
#pragma unroll
        for (int pt = 0; pt < PT; ++pt)
            acc[pt] = __builtin_amdgcn_mfma_f32_16x16x32_bf16(a0c, bx[pt][0], ne2c, 0, 0, 0);
#pragma unroll
        for (int pt = 0; pt < PT; ++pt)
            acc[pt] = __builtin_amdgcn_mfma_f32_16x16x32_bf16(a1c, bx[pt][1], acc[pt], 0, 0, 0);
#pragma unroll
        for (int pt = 0; pt < PT; ++pt) {
            const float m01 = fmaxf(acc[pt][0], acc[pt][1]);
            const float m23 = fmaxf(acc[pt][2], acc[pt][3]);
            M[pt] = fmaxf(M[pt], fmaxf(m01, m23));
        }
    }

    // ---- merge across the 4 lanes holding the same position column ----
    float thr[PT];
#pragma unroll
    for (int pt = 0; pt < PT; ++pt) {
        float m = M[pt];
        m = fmaxf(m, __shfl_xor(m, 16, 64));
        m = fmaxf(m, __shfl_xor(m, 32, 64));
        thr[pt] = m - DELTA;
    }

    // ---- pass 2: bitwise-identical recompute, enqueue candidates ----
    a0n = *(const short8v*)(ebfB + l15 * 128 + lg * 16);
    a1n = *(const short8v*)(ebfB + l15 * 128 + 64 + lg * 16);
    ne2n = *(const float4v*)(ne2h + lg * 4);

    for (int ct = 0; ct < 32; ++ct) {
        const short8v a0c = a0n, a1c = a1n;
        const float4v ne2c = ne2n;
        if (ct < 31) {
            const char* p = ebfB + ((ct + 1) * 16 + l15) * 128 + lg * 16;
            a0n = *(const short8v*)p;
            a1n = *(const short8v*)(p + 64);
            ne2n = *(const float4v*)(ne2h + (ct + 1) * 16 + lg * 4);
        }
        float4v acc[PT];
#pragma unroll
        for (int pt = 0; pt < PT; ++pt)
            acc[pt] = __builtin_amdgcn_mfma_f32_16x16x32_bf16(a0c, bx[pt][0], ne2c, 0, 0, 0);
#pragma unroll
        for (int pt = 0; pt < PT; ++pt)
            acc[pt] = __builtin_amdgcn_mfma_f32_16x16x32_bf16(a1c, bx[pt][1], acc[pt], 0, 0, 0);
#pragma unroll
        for (int pt = 0; pt < PT; ++pt) {
            const float m01 = fmaxf(acc[pt][0], acc[pt][1]);
            const float m23 = fmaxf(acc[pt][2], acc[pt][3]);
            const float mx  = fmaxf(m01, m23);
            if (__any(mx >= thr[pt])) {
#pragma unroll
                for (int r = 0; r < 4; ++r) {
                    if (acc[pt][r] >= thr[pt]) {
                        const unsigned idx  = atomicAdd(&qcnt, 1u);
                        const unsigned code = (unsigned)(ct * 16 + lg * 4 + r);
                        const unsigned pos  = (unsigned)(wbase + pt * 16 + l15);
                        if (idx < QCAP) qbuf[idx] = (pos << 9) | code;
                    }
                }
            }
        }
    }

    __syncthreads();

    // ---- drain: fp32 rescore of candidates, resolve winner per position ----
    const unsigned nq = min(qcnt, (unsigned)QCAP);
    for (unsigned i = tid; i < nq; i += 256) {
        const unsigned e = qbuf[i];
        const unsigned p = e >> 9, k = e & 511u;
        const float* er = emb + k * DD;
        float a0 = 0.f, a1 = 0.f, a2 = 0.f, a3 = 0.f;
#pragma unroll
        for (int d = 0; d < DD; d += 4) {
            a0 = fmaf(featB[(size_t)(d    ) * HWHW + hwb + p], er[d    ], a0);
            a1 = fmaf(featB[(size_t)(d + 1) * HWHW + hwb + p], er[d + 1], a1);
            a2 = fmaf(featB[(size_t)(d + 2) * HWHW + hwb + p], er[d + 2], a2);
            a3 = fmaf(featB[(size_t)(d + 3) * HWHW + hwb + p], er[d + 3], a3);
        }
        const float sc = ((a0 + a1) + (a2 + a3)) + ne2h[k];
        const unsigned long long key =
            ((unsigned long long)f2o(sc) << 32) | (unsigned long long)(511u - k);
        atomicMax(&sbest[p], key);   // ties -> larger (511-k) -> smaller k (first-min)
    }

    __syncthreads();

    // ---- epilogue: st = e[k*] (exact), loss from in-register bf16 x ----
    float lsum = 0.f;
#pragma unroll
    for (int pt = 0; pt < PT; ++pt) {
        const int pl = wbase + pt * 16 + l15;
        const int hw = hwb + pl;
        const unsigned long long key = sbest[pl];
        const unsigned k = 511u - (unsigned)key;
        const float* er = emb + k * DD;
#pragma unroll
        for (int h = 0; h < 2; ++h) {
            const short8v xs = bx[pt][h];
#pragma unroll
            for (int jj = 0; jj < 2; ++jj) {
                const float4v ev = *(const float4v*)(er + h * 32 + lg * 8 + jj * 4);
#pragma unroll
                for (int c = 0; c < 4; ++c) {
                    const int j = jj * 4 + c;
                    const int d = h * 32 + lg * 8 + j;
                    const float q = ev[c];
                    outB[(size_t)d * HWHW + hw] = q;
                    const float diff = q - bf2f((unsigned short)xs[j]);
                    lsum = fmaf(diff, diff, lsum);
                }
            }
        }
    }

#pragma unroll
    for (int off = 32; off > 0; off >>= 1) lsum += __shfl_down(lsum, off, 64);
    if (lane == 0) wsum[wid] = lsum;
    __syncthreads();
    if (tid == 0)
        atomicAdd(loss, (wsum[0] + wsum[1] + wsum[2] + wsum[3]) * LOSS_SCALE);
}

// ---------------------------------------------------------------------------
extern "C" void kernel_launch(void* const* d_in, const int* in_sizes, int n_in,
                              void* d_out, int out_size, void* d_ws, size_t ws_size,
                              hipStream_t stream) {
    const float* feat = (const float*)d_in[0];   // (32,64,64,64) fp32
    const float* emb  = (const float*)d_in[1];   // (512,64) fp32
    float* out  = (float*)d_out;                 // [0..NELEM) = st, [NELEM] = loss
    float* loss = out + NELEM;

    unsigned short* ebf  = (unsigned short*)d_ws;                // 64 KiB bf16 codebook
    float*          ne2h = (float*)((char*)d_ws + 64 * 1024);    // 2 KiB, -|e|^2/2

    hipMemsetAsync(loss, 0, sizeof(float), stream);
    vq_prep<<<dim3(32), dim3(256), 0, stream>>>(emb, ebf, ne2h);
    vq_main<<<dim3(NBLK), dim3(256), 0, stream>>>(feat, emb, ebf, ne2h, out, loss);
}